// Round 6
// baseline (726.599 us; speedup 1.0000x reference)
//
#include <hip/hip_runtime.h>
#include <hip/hip_bf16.h>

typedef __attribute__((ext_vector_type(8))) short bf16x8;
typedef __attribute__((ext_vector_type(16))) float f32x16;

#define GLD16(g, s) __builtin_amdgcn_global_load_lds( \
    (const __attribute__((address_space(1))) void*)(g), \
    (__attribute__((address_space(3))) void*)(s), 16, 0, 0)

#define SBAR() __builtin_amdgcn_sched_barrier(0)
#define WAIT_LGKM(n) do { asm volatile("s_waitcnt lgkmcnt(" #n ")" ::: "memory"); SBAR(); } while (0)

static constexpr int kB  = 128;
static constexpr int kC  = 1280;
static constexpr int kHW = 256;

// Phase-interleaved GEMM: C(M,N) = A(M,K)*Bt(N,K)^T.
// BM=BN=256, BK=64; 512 thr = 8 waves (2M x 4N), wave tile 128x64.
// MFMA 32x32x16 (acc 4x2 x f32x16). 2 LDS slots x 64KB. One s_barrier +
// vmcnt(0) per K-tile (staging issued a full compute-tile earlier); inside,
// 4 k-slice phases (8 MFMA each) with P/Q reg double-buffer and counted
// lgkmcnt(6). All addresses hoisted out of the loop. XOR-swizzled LDS.
// OUT_MODE: 0=bf16 rowmajor, 1=f32 rowmajor, 2=bf16 conv, 3=f32 conv alpha*()+resid
// BIAS_MODE: 0=none, 1=bias[col], 2=bias[row]
// ORDER: 0 = m-fastest (B operand large), 1 = n-fastest (A operand large)
template<int OUT_MODE, int BIAS_MODE, int ORDER>
__global__ __launch_bounds__(512, 2) void gemm_r(
    const __hip_bfloat16* __restrict__ A,
    const __hip_bfloat16* __restrict__ Bt,
    void* __restrict__ outp,
    const float* __restrict__ bias,
    const float* __restrict__ resid,
    const float* __restrict__ alphap,
    int M, int N, int K,
    int ldA, int ldB, long sA, long sB, long sC, int ldC)
{
    extern __shared__ char smem[];   // 2 slots x 65536
    const int t = threadIdx.x;
    const int w = t >> 6, l = t & 63;
    const int l31 = l & 31, lhi = l >> 5;
    const int wr = w >> 2, wc = w & 3;   // 2M x 4N waves
    const int z = blockIdx.z;
    const int nbm = M >> 8, nbn = N >> 8;
    const int nwg = nbm * nbn;
    int f = blockIdx.x;
    {   // bijective XCD swizzle (m204)
        const int q8 = nwg >> 3, r8 = nwg & 7;
        const int xcd = f & 7, rank = f >> 3;
        f = (xcd < r8 ? xcd * (q8 + 1) : r8 * (q8 + 1) + (xcd - r8) * q8) + rank;
    }
    long m0, n0;
    if (ORDER == 0) { m0 = (long)(f % nbm) << 8; n0 = (long)(f / nbm) << 8; }
    else            { n0 = (long)(f % nbn) << 8; m0 = (long)(f / nbn) << 8; }
    const char* Azb = (const char*)(A + (long)z * sA);
    const char* Bzb = (const char*)(Bt + (long)z * sB);

    // ---- hoisted staging addresses (advance +128B per K-tile) ----
    const char* pa[4];
    const char* pb[4];
    int ldsd[4];
    #pragma unroll
    for (int i = 0; i < 4; ++i) {
        const int d = i * 8192 + t * 16;
        const int row = d >> 7;
        const int cb = (d & 127) ^ ((row & 7) << 4);   // inverse-swizzled source
        pa[i] = Azb + ((m0 + row) * (long)ldA) * 2 + cb;
        pb[i] = Bzb + ((n0 + row) * (long)ldB) * 2 + cb;
        ldsd[i] = d;
    }
    auto stage = [&](int slot) {
        char* base = smem + slot * 65536;
        #pragma unroll
        for (int i = 0; i < 4; ++i) GLD16(pa[i], base + ldsd[i]);
        #pragma unroll
        for (int i = 0; i < 4; ++i) GLD16(pb[i], base + 32768 + ldsd[i]);
        #pragma unroll
        for (int i = 0; i < 4; ++i) { pa[i] += 128; pb[i] += 128; }
    };

    // ---- hoisted LDS read offsets ----
    // LDS[row*128 + (c ^ ((row&7)<<4))] holds A[row][byte c]; row&7==l&7 for
    // all our rows, and c = ks*32 + (l>>5)*16  ->  off = base + (s0 ^ (ks*32))
    const int mask = (l & 7) << 4;
    const int s0 = (lhi << 4) ^ mask;
    int offA[4], offB[4];
    #pragma unroll
    for (int ks = 0; ks < 4; ++ks) {
        offA[ks] = (wr * 128 + l31) * 128 + (s0 ^ (ks << 5));
        offB[ks] = 32768 + (wc * 64 + l31) * 128 + (s0 ^ (ks << 5));
    }

#define RD_A(dst, bs_, ks) do { const char* p_ = (bs_) + offA[ks]; \
    dst[0] = *(const bf16x8*)(p_);         dst[1] = *(const bf16x8*)(p_ + 4096); \
    dst[2] = *(const bf16x8*)(p_ + 8192);  dst[3] = *(const bf16x8*)(p_ + 12288); } while (0)
#define RD_B(dst, bs_, ks) do { const char* p_ = (bs_) + offB[ks]; \
    dst[0] = *(const bf16x8*)(p_);         dst[1] = *(const bf16x8*)(p_ + 4096); } while (0)
#define MM(ar, br) do { __builtin_amdgcn_s_setprio(1); \
    _Pragma("unroll") for (int mi = 0; mi < 4; ++mi) \
    _Pragma("unroll") for (int ni = 0; ni < 2; ++ni) \
        acc[mi][ni] = __builtin_amdgcn_mfma_f32_32x32x16_bf16(ar[mi], br[ni], acc[mi][ni], 0, 0, 0); \
    __builtin_amdgcn_s_setprio(0); SBAR(); } while (0)

    f32x16 acc[4][2] = {};
    const int nK = K >> 6;
    stage(0);

    for (int tk = 0; tk < nK; ++tk) {
        const int s = tk & 1;
        asm volatile("s_waitcnt vmcnt(0)" ::: "memory");   // own slot-s loads done
        SBAR();
        __builtin_amdgcn_s_barrier();                      // everyone's done
        SBAR();
        if (tk + 1 < nK) stage(s ^ 1);                     // issue next tile early
        SBAR();

        const char* bs_ = smem + s * 65536;
        bf16x8 aP[4], bP[2], aQ[4], bQ[2];
        RD_B(bP, bs_, 0); RD_A(aP, bs_, 0);                // 6 reads (ks0)
        RD_B(bQ, bs_, 1); RD_A(aQ, bs_, 1);                // 6 reads (ks1)
        WAIT_LGKM(6);  MM(aP, bP);                         // ks0 (ks1 in flight)
        RD_B(bP, bs_, 2); RD_A(aP, bs_, 2);                // 6 reads (ks2)
        WAIT_LGKM(6);  MM(aQ, bQ);                         // ks1 (ks2 in flight)
        RD_B(bQ, bs_, 3); RD_A(aQ, bs_, 3);                // 6 reads (ks3)
        WAIT_LGKM(6);  MM(aP, bP);                         // ks2 (ks3 in flight)
        WAIT_LGKM(0);  MM(aQ, bQ);                         // ks3
    }

    const float alpha = (OUT_MODE == 3) ? alphap[0] : 0.0f;
    #pragma unroll
    for (int mi = 0; mi < 4; ++mi) {
        #pragma unroll
        for (int ni = 0; ni < 2; ++ni) {
            #pragma unroll
            for (int r = 0; r < 16; ++r) {
                const long row = m0 + wr * 128 + mi * 32 + ((r & 3) + 8 * (r >> 2) + 4 * lhi);
                const long col = n0 + wc * 64 + ni * 32 + l31;
                float vv = acc[mi][ni][r];
                if (BIAS_MODE == 1) vv += bias[col];
                if (BIAS_MODE == 2) vv += bias[row];
                if (OUT_MODE == 0) {
                    ((__hip_bfloat16*)outp)[(long)z * sC + row * ldC + col] = __float2bfloat16(vv);
                } else if (OUT_MODE == 1) {
                    ((float*)outp)[(long)z * sC + row * ldC + col] = vv;
                } else if (OUT_MODE == 2) {
                    const long addr = (col >> 8) * (long)(kC * kHW) + row * kHW + (col & 255);
                    ((__hip_bfloat16*)outp)[addr] = __float2bfloat16(vv);
                } else {
                    const long addr = (col >> 8) * (long)(kC * kHW) + row * kHW + (col & 255);
                    ((float*)outp)[addr] = alpha * vv + resid[addr];
                }
            }
        }
    }
#undef RD_A
#undef RD_B
#undef MM
}

// x (B, C, HW) f32  ->  xT (B*HW, C) bf16
__global__ __launch_bounds__(256) void transpose_x(
    const float* __restrict__ x, __hip_bfloat16* __restrict__ xT)
{
    __shared__ float tile[64][65];
    const int b = blockIdx.z;
    const int c0 = blockIdx.x * 64;
    const int p0 = blockIdx.y * 64;
    const int tj = threadIdx.x & 63;
    const int ti = threadIdx.x >> 6;
    const float* xb = x + ((long)b * kC + c0) * kHW + p0;
    #pragma unroll
    for (int i = 0; i < 16; ++i) {
        const int c = i * 4 + ti;
        tile[c][tj] = xb[(long)c * kHW + tj];
    }
    __syncthreads();
    __hip_bfloat16* o = xT + ((long)(b * kHW + p0)) * kC + c0;
    #pragma unroll
    for (int i = 0; i < 16; ++i) {
        const int p = i * 4 + ti;
        o[(long)p * kC + tj] = __float2bfloat16(tile[tj][p]);
    }
}

__global__ __launch_bounds__(256) void convert_f32_bf16(
    const float* __restrict__ s, __hip_bfloat16* __restrict__ d)
{
    const int i = (blockIdx.x * 256 + threadIdx.x) * 4;
    const float4 f = *reinterpret_cast<const float4*>(s + i);
    d[i + 0] = __float2bfloat16(f.x);
    d[i + 1] = __float2bfloat16(f.y);
    d[i + 2] = __float2bfloat16(f.z);
    d[i + 3] = __float2bfloat16(f.w);
}

__global__ __launch_bounds__(256) void concat_bias(
    const float* __restrict__ bk, const float* __restrict__ bq, float* __restrict__ bc)
{
    const int i = blockIdx.x * 256 + threadIdx.x;  // grid 10*256 = 2560
    bc[i] = (i < 1280) ? bk[i] : bq[i - 1280];
}

// softmax over BATCH axis: scores (B,256,256) f32 -> attn bf16
__global__ __launch_bounds__(256) void softmax_batch(
    const float* __restrict__ scores, __hip_bfloat16* __restrict__ attn)
{
    const int pos = blockIdx.x * 256 + threadIdx.x;
    float m = -3.0e38f, s = 0.0f;
    for (int b = 0; b < kB; ++b) {
        const float v = scores[(long)b * 65536 + pos];
        const float mn = fmaxf(m, v);
        s = s * __expf(m - mn) + __expf(v - mn);
        m = mn;
    }
    const float rinv = 1.0f / s;
    for (int b = 0; b < kB; ++b) {
        const float v = scores[(long)b * 65536 + pos];
        attn[(long)b * 65536 + pos] = __float2bfloat16(__expf(v - m) * rinv);
    }
}

extern "C" void kernel_launch(void* const* d_in, const int* in_sizes, int n_in,
                              void* d_out, int out_size, void* d_ws, size_t ws_size,
                              hipStream_t stream)
{
    const float* x  = (const float*)d_in[0];
    const float* Wk = (const float*)d_in[1];
    const float* bk = (const float*)d_in[2];
    const float* Wq = (const float*)d_in[3];
    const float* bq = (const float*)d_in[4];
    const float* Wv = (const float*)d_in[5];
    const float* bv = (const float*)d_in[6];
    const float* Wr = (const float*)d_in[7];
    const float* br = (const float*)d_in[8];
    const float* al = (const float*)d_in[9];

    char* ws = (char*)d_ws;
    __hip_bfloat16* xT   = (__hip_bfloat16*)(ws);               // 83.9MB; dead after V GEMM
    float*          sc   = (float*)(ws);                        // aliases xT (33.5MB)
    __hip_bfloat16* kqT  = (__hip_bfloat16*)(ws + 83886080L);   // (32768,2560) 167.8MB
    __hip_bfloat16* attn = (__hip_bfloat16*)(ws + 83886080L);   // aliases kqT (16.8MB)
    __hip_bfloat16* att2 = (__hip_bfloat16*)(ws + 100663296L);  // aliases kqT tail (83.9MB)
    __hip_bfloat16* vv   = (__hip_bfloat16*)(ws + 251658240L);  // 83.9MB
    __hip_bfloat16* Wcatb= (__hip_bfloat16*)(ws + 335544320L);  // (2560,1280)
    __hip_bfloat16* Wvb  = Wcatb + 2560 * 1280;
    __hip_bfloat16* Wrb  = Wvb + 1280 * 1280;
    float*          bcat = (float*)(ws + 348651520L);           // 2560 f32

    const int SMEM = 131072;
    hipFuncSetAttribute((const void*)gemm_r<0,1,1>, hipFuncAttributeMaxDynamicSharedMemorySize, SMEM);
    hipFuncSetAttribute((const void*)gemm_r<2,2,0>, hipFuncAttributeMaxDynamicSharedMemorySize, SMEM);
    hipFuncSetAttribute((const void*)gemm_r<1,0,0>, hipFuncAttributeMaxDynamicSharedMemorySize, SMEM);
    hipFuncSetAttribute((const void*)gemm_r<0,0,0>, hipFuncAttributeMaxDynamicSharedMemorySize, SMEM);
    hipFuncSetAttribute((const void*)gemm_r<3,2,0>, hipFuncAttributeMaxDynamicSharedMemorySize, SMEM);

    convert_f32_bf16<<<1600, 256, 0, stream>>>(Wk, Wcatb);
    convert_f32_bf16<<<1600, 256, 0, stream>>>(Wq, Wcatb + 1638400);
    convert_f32_bf16<<<1600, 256, 0, stream>>>(Wv, Wvb);
    convert_f32_bf16<<<1600, 256, 0, stream>>>(Wr, Wrb);
    concat_bias<<<10, 256, 0, stream>>>(bk, bq, bcat);
    transpose_x<<<dim3(20, 4, 128), 256, 0, stream>>>(x, xT);

    // fused K|Q: kqT (32768, 2560) = xT * Wcat^T + bcat[col]; A large -> ORDER=1
    gemm_r<0, 1, 1><<<dim3(1280, 1, 1), 512, SMEM, stream>>>(xT, Wcatb, kqT, bcat, nullptr, nullptr,
        32768, 2560, 1280, 1280, 1280, 0, 0, 0, 2560);
    // v (B,C,HW) = Wv * xT^T + bv[row];  B large -> ORDER=0
    gemm_r<2, 2, 0><<<dim3(640, 1, 1), 512, SMEM, stream>>>(Wvb, xT, vv, bv, nullptr, nullptr,
        1280, 32768, 1280, 1280, 1280, 0, 0, 0, 0);
    // scores (B,256,256) f32 = kT[b] * qT[b]^T
    gemm_r<1, 0, 0><<<dim3(1, 1, 128), 512, SMEM, stream>>>(kqT, kqT + 1280, sc, nullptr, nullptr, nullptr,
        256, 256, 1280, 2560, 2560, 655360, 655360, 65536, 256);
    softmax_batch<<<256, 256, 0, stream>>>(sc, attn);
    // att2 (B,256,1280) = attn[b] * v[b]^T
    gemm_r<0, 0, 0><<<dim3(5, 1, 128), 512, SMEM, stream>>>(attn, vv, att2, nullptr, nullptr, nullptr,
        256, 1280, 256, 256, 256, 65536, 327680, 327680, 1280);
    // out f32 (B,C,HW) = alpha*(Wr*att2^T + br[row]) + x;  B large -> ORDER=0
    gemm_r<3, 2, 0><<<dim3(640, 1, 1), 512, SMEM, stream>>>(Wrb, att2, d_out, br, x, al,
        1280, 32768, 1280, 1280, 1280, 0, 0, 0, 0);
}

// Round 7
// 713.605 us; speedup vs baseline: 1.0182x; 1.0182x over previous
//
#include <hip/hip_runtime.h>
#include <hip/hip_bf16.h>

typedef __attribute__((ext_vector_type(8))) short bf16x8;
typedef __attribute__((ext_vector_type(4))) float f32x4;

#define GLD16(g, s) __builtin_amdgcn_global_load_lds( \
    (const __attribute__((address_space(1))) void*)(g), \
    (__attribute__((address_space(3))) void*)(s), 16, 0, 0)

#define SBAR() __builtin_amdgcn_sched_barrier(0)
#define BARRIER() __builtin_amdgcn_s_barrier()
#define WAIT_LGKM0() do { asm volatile("s_waitcnt lgkmcnt(0)" ::: "memory"); SBAR(); } while (0)

static constexpr int kB  = 128;
static constexpr int kC  = 1280;
static constexpr int kHW = 256;

// 8-phase-style GEMM (m201 port): C(M,N) = A(M,K)*Bt(N,K)^T.
// BM=BN=256, BK=64; 512 thr = 8 waves (2M x 4N), wave tile 128x64,
// MFMA 16x16x32 (conflict-free under (row&7)<<4 swizzle; measured R2-R5).
// Per K-tile: 4 phases {ds_read subtile | stage 4 gld_lds (ph0/ph1) ->
// barrier -> lgkmcnt(0) -> setprio 16 MFMA -> barrier}. Next tile staged in
// ph0-ph1 so ph3's vmcnt(0) has ~2 phases of slack. Addresses hoisted.
// OUT_MODE: 0=bf16 rowmajor, 1=f32 rowmajor, 2=bf16 conv, 3=f32 conv alpha*()+resid
// BIAS_MODE: 0=none, 1=bias[col], 2=bias[row]
// ORDER: 0 = m-fastest (B operand large), 1 = n-fastest (A operand large)
template<int OUT_MODE, int BIAS_MODE, int ORDER>
__global__ __launch_bounds__(512, 2) void gemm_s(
    const __hip_bfloat16* __restrict__ A,
    const __hip_bfloat16* __restrict__ Bt,
    void* __restrict__ outp,
    const float* __restrict__ bias,
    const float* __restrict__ resid,
    const float* __restrict__ alphap,
    int M, int N, int K,
    int ldA, int ldB, long sA, long sB, long sC, int ldC)
{
    extern __shared__ char smem[];   // 2 slots x 65536 (A 32K + B 32K each)
    const int t = threadIdx.x;
    const int w = t >> 6, l = t & 63;
    const int q = l >> 4, r16 = l & 15;
    const int wr = w >> 2, wc = w & 3;   // 2M x 4N waves
    const int z = blockIdx.z;
    const int nbm = M >> 8, nbn = N >> 8;
    const int nwg = nbm * nbn;
    int f = blockIdx.x;
    {   // bijective XCD swizzle (m204)
        const int q8 = nwg >> 3, r8 = nwg & 7;
        const int xcd = f & 7, rank = f >> 3;
        f = (xcd < r8 ? xcd * (q8 + 1) : r8 * (q8 + 1) + (xcd - r8) * q8) + rank;
    }
    long m0, n0;
    if (ORDER == 0) { m0 = (long)(f % nbm) << 8; n0 = (long)(f / nbm) << 8; }
    else            { n0 = (long)(f % nbn) << 8; m0 = (long)(f / nbn) << 8; }
    const char* Azb = (const char*)(A + (long)z * sA);
    const char* Bzb = (const char*)(Bt + (long)z * sB);

    // ---- hoisted staging addresses (advance +128B per K-tile) ----
    const char* pa[4];
    const char* pb[4];
    int ldsd[4];
    #pragma unroll
    for (int i = 0; i < 4; ++i) {
        const int d = i * 8192 + t * 16;
        const int row = d >> 7;
        const int cb = (d & 127) ^ ((row & 7) << 4);   // inverse-swizzled source
        pa[i] = Azb + ((m0 + row) * (long)ldA) * 2 + cb;
        pb[i] = Bzb + ((n0 + row) * (long)ldB) * 2 + cb;
        ldsd[i] = d;
    }

    // ---- hoisted LDS read constants ----
    // frag addr(mi,kk) = slot + (wrbase + mi*16 + r16)*128 + (cx ^ (kk<<6))
    const int cx  = (q << 4) ^ ((l & 7) << 4);
    const int cK0 = cx, cK1 = cx ^ 64;
    const int arow = (wr * 128 + r16) * 128;           // + mih*8192 + j*2048
    const int brow = 32768 + (wc * 64 + r16) * 128;    // + ni*2048

#define DSA(dst, sb, mih, ckk) do { const char* p_ = (sb) + arow + (ckk) + (mih) * 8192; \
    dst[0] = *(const bf16x8*)(p_);        dst[1] = *(const bf16x8*)(p_ + 2048); \
    dst[2] = *(const bf16x8*)(p_ + 4096); dst[3] = *(const bf16x8*)(p_ + 6144); } while (0)
#define DSB(dst, sb, ckk) do { const char* p_ = (sb) + brow + (ckk); \
    dst[0] = *(const bf16x8*)(p_);        dst[1] = *(const bf16x8*)(p_ + 2048); \
    dst[2] = *(const bf16x8*)(p_ + 4096); dst[3] = *(const bf16x8*)(p_ + 6144); } while (0)
#define MM16(ar, br, mih) do { __builtin_amdgcn_s_setprio(1); \
    _Pragma("unroll") for (int j = 0; j < 4; ++j) \
    _Pragma("unroll") for (int ni = 0; ni < 4; ++ni) \
        acc[(mih) * 4 + j][ni] = __builtin_amdgcn_mfma_f32_16x16x32_bf16( \
            ar[j], br[ni], acc[(mih) * 4 + j][ni], 0, 0, 0); \
    __builtin_amdgcn_s_setprio(0); SBAR(); } while (0)

    f32x4 acc[8][4] = {};
    const int nK = K >> 6;

    // prologue: stage tile 0 fully into slot 0
    {
        char* base = smem;
        #pragma unroll
        for (int i = 0; i < 4; ++i) GLD16(pa[i], base + ldsd[i]);
        #pragma unroll
        for (int i = 0; i < 4; ++i) GLD16(pb[i], base + 32768 + ldsd[i]);
        #pragma unroll
        for (int i = 0; i < 4; ++i) { pa[i] += 128; pb[i] += 128; }
    }
    asm volatile("s_waitcnt vmcnt(0)" ::: "memory");
    SBAR();
    BARRIER();
    SBAR();

    for (int tk = 0; tk < nK; ++tk) {
        char* sb = smem + (tk & 1) * 65536;
        char* nb = smem + ((tk & 1) ^ 1) * 65536;
        const bool stg = (tk + 1 < nK);
        bf16x8 a0[4], a1[4], b0[4], b1[4];

        // ---- phase 0: kk0, mi 0-3 (+ stage next-tile A) ----
        DSB(b0, sb, cK0);
        DSA(a0, sb, 0, cK0);
        if (stg) {
            #pragma unroll
            for (int i = 0; i < 4; ++i) GLD16(pa[i], nb + ldsd[i]);
        }
        SBAR(); BARRIER(); WAIT_LGKM0();
        MM16(a0, b0, 0);
        BARRIER(); SBAR();

        // ---- phase 1: kk0, mi 4-7 (+ stage next-tile B) ----
        DSA(a1, sb, 1, cK0);
        if (stg) {
            #pragma unroll
            for (int i = 0; i < 4; ++i) GLD16(pb[i], nb + 32768 + ldsd[i]);
            #pragma unroll
            for (int i = 0; i < 4; ++i) { pa[i] += 128; pb[i] += 128; }
        }
        SBAR(); BARRIER(); WAIT_LGKM0();
        MM16(a1, b0, 1);
        BARRIER(); SBAR();

        // ---- phase 2: kk1, mi 0-3 ----
        DSB(b1, sb, cK1);
        DSA(a0, sb, 0, cK1);
        SBAR(); BARRIER(); WAIT_LGKM0();
        MM16(a0, b1, 0);
        BARRIER(); SBAR();

        // ---- phase 3: kk1, mi 4-7 (+ wait next tile landed) ----
        DSA(a1, sb, 1, cK1);
        asm volatile("s_waitcnt vmcnt(0)" ::: "memory");  // issued ph0-ph1, ~2 phases ago
        SBAR(); BARRIER(); WAIT_LGKM0();
        MM16(a1, b1, 1);
        BARRIER(); SBAR();
    }

    const float alpha = (OUT_MODE == 3) ? alphap[0] : 0.0f;
    #pragma unroll
    for (int mi = 0; mi < 8; ++mi) {
        #pragma unroll
        for (int ni = 0; ni < 4; ++ni) {
            #pragma unroll
            for (int r = 0; r < 4; ++r) {
                const long row = m0 + wr * 128 + mi * 16 + q * 4 + r;
                const long col = n0 + wc * 64 + ni * 16 + r16;
                float vv = acc[mi][ni][r];
                if (BIAS_MODE == 1) vv += bias[col];
                if (BIAS_MODE == 2) vv += bias[row];
                if (OUT_MODE == 0) {
                    ((__hip_bfloat16*)outp)[(long)z * sC + row * ldC + col] = __float2bfloat16(vv);
                } else if (OUT_MODE == 1) {
                    ((float*)outp)[(long)z * sC + row * ldC + col] = vv;
                } else if (OUT_MODE == 2) {
                    const long addr = (col >> 8) * (long)(kC * kHW) + row * kHW + (col & 255);
                    ((__hip_bfloat16*)outp)[addr] = __float2bfloat16(vv);
                } else {
                    const long addr = (col >> 8) * (long)(kC * kHW) + row * kHW + (col & 255);
                    ((float*)outp)[addr] = alpha * vv + resid[addr];
                }
            }
        }
    }
#undef DSA
#undef DSB
#undef MM16
}

// x (B, C, HW) f32  ->  xT (B*HW, C) bf16
__global__ __launch_bounds__(256) void transpose_x(
    const float* __restrict__ x, __hip_bfloat16* __restrict__ xT)
{
    __shared__ float tile[64][65];
    const int b = blockIdx.z;
    const int c0 = blockIdx.x * 64;
    const int p0 = blockIdx.y * 64;
    const int tj = threadIdx.x & 63;
    const int ti = threadIdx.x >> 6;
    const float* xb = x + ((long)b * kC + c0) * kHW + p0;
    #pragma unroll
    for (int i = 0; i < 16; ++i) {
        const int c = i * 4 + ti;
        tile[c][tj] = xb[(long)c * kHW + tj];
    }
    __syncthreads();
    __hip_bfloat16* o = xT + ((long)(b * kHW + p0)) * kC + c0;
    #pragma unroll
    for (int i = 0; i < 16; ++i) {
        const int p = i * 4 + ti;
        o[(long)p * kC + tj] = __float2bfloat16(tile[tj][p]);
    }
}

__global__ __launch_bounds__(256) void convert_f32_bf16(
    const float* __restrict__ s, __hip_bfloat16* __restrict__ d)
{
    const int i = (blockIdx.x * 256 + threadIdx.x) * 4;
    const float4 f = *reinterpret_cast<const float4*>(s + i);
    d[i + 0] = __float2bfloat16(f.x);
    d[i + 1] = __float2bfloat16(f.y);
    d[i + 2] = __float2bfloat16(f.z);
    d[i + 3] = __float2bfloat16(f.w);
}

__global__ __launch_bounds__(256) void concat_bias(
    const float* __restrict__ bk, const float* __restrict__ bq, float* __restrict__ bc)
{
    const int i = blockIdx.x * 256 + threadIdx.x;  // grid 10*256 = 2560
    bc[i] = (i < 1280) ? bk[i] : bq[i - 1280];
}

// softmax over BATCH axis: scores (B,256,256) f32 -> attn bf16
__global__ __launch_bounds__(256) void softmax_batch(
    const float* __restrict__ scores, __hip_bfloat16* __restrict__ attn)
{
    const int pos = blockIdx.x * 256 + threadIdx.x;
    float m = -3.0e38f, s = 0.0f;
    for (int b = 0; b < kB; ++b) {
        const float v = scores[(long)b * 65536 + pos];
        const float mn = fmaxf(m, v);
        s = s * __expf(m - mn) + __expf(v - mn);
        m = mn;
    }
    const float rinv = 1.0f / s;
    for (int b = 0; b < kB; ++b) {
        const float v = scores[(long)b * 65536 + pos];
        attn[(long)b * 65536 + pos] = __float2bfloat16(__expf(v - m) * rinv);
    }
}

extern "C" void kernel_launch(void* const* d_in, const int* in_sizes, int n_in,
                              void* d_out, int out_size, void* d_ws, size_t ws_size,
                              hipStream_t stream)
{
    const float* x  = (const float*)d_in[0];
    const float* Wk = (const float*)d_in[1];
    const float* bk = (const float*)d_in[2];
    const float* Wq = (const float*)d_in[3];
    const float* bq = (const float*)d_in[4];
    const float* Wv = (const float*)d_in[5];
    const float* bv = (const float*)d_in[6];
    const float* Wr = (const float*)d_in[7];
    const float* br = (const float*)d_in[8];
    const float* al = (const float*)d_in[9];

    char* ws = (char*)d_ws;
    __hip_bfloat16* xT   = (__hip_bfloat16*)(ws);               // 83.9MB; dead after V GEMM
    float*          sc   = (float*)(ws);                        // aliases xT (33.5MB)
    __hip_bfloat16* kqT  = (__hip_bfloat16*)(ws + 83886080L);   // (32768,2560) 167.8MB
    __hip_bfloat16* attn = (__hip_bfloat16*)(ws + 83886080L);   // aliases kqT (16.8MB)
    __hip_bfloat16* att2 = (__hip_bfloat16*)(ws + 100663296L);  // aliases kqT tail (83.9MB)
    __hip_bfloat16* vv   = (__hip_bfloat16*)(ws + 251658240L);  // 83.9MB
    __hip_bfloat16* Wcatb= (__hip_bfloat16*)(ws + 335544320L);  // (2560,1280)
    __hip_bfloat16* Wvb  = Wcatb + 2560 * 1280;
    __hip_bfloat16* Wrb  = Wvb + 1280 * 1280;
    float*          bcat = (float*)(ws + 348651520L);           // 2560 f32

    const int SMEM = 131072;
    hipFuncSetAttribute((const void*)gemm_s<0,1,1>, hipFuncAttributeMaxDynamicSharedMemorySize, SMEM);
    hipFuncSetAttribute((const void*)gemm_s<2,2,0>, hipFuncAttributeMaxDynamicSharedMemorySize, SMEM);
    hipFuncSetAttribute((const void*)gemm_s<1,0,0>, hipFuncAttributeMaxDynamicSharedMemorySize, SMEM);
    hipFuncSetAttribute((const void*)gemm_s<0,0,0>, hipFuncAttributeMaxDynamicSharedMemorySize, SMEM);
    hipFuncSetAttribute((const void*)gemm_s<3,2,0>, hipFuncAttributeMaxDynamicSharedMemorySize, SMEM);

    convert_f32_bf16<<<1600, 256, 0, stream>>>(Wk, Wcatb);
    convert_f32_bf16<<<1600, 256, 0, stream>>>(Wq, Wcatb + 1638400);
    convert_f32_bf16<<<1600, 256, 0, stream>>>(Wv, Wvb);
    convert_f32_bf16<<<1600, 256, 0, stream>>>(Wr, Wrb);
    concat_bias<<<10, 256, 0, stream>>>(bk, bq, bcat);
    transpose_x<<<dim3(20, 4, 128), 256, 0, stream>>>(x, xT);

    // fused K|Q: kqT (32768, 2560) = xT * Wcat^T + bcat[col]; A large -> ORDER=1
    gemm_s<0, 1, 1><<<dim3(1280, 1, 1), 512, SMEM, stream>>>(xT, Wcatb, kqT, bcat, nullptr, nullptr,
        32768, 2560, 1280, 1280, 1280, 0, 0, 0, 2560);
    // v (B,C,HW) = Wv * xT^T + bv[row];  B large -> ORDER=0
    gemm_s<2, 2, 0><<<dim3(640, 1, 1), 512, SMEM, stream>>>(Wvb, xT, vv, bv, nullptr, nullptr,
        1280, 32768, 1280, 1280, 1280, 0, 0, 0, 0);
    // scores (B,256,256) f32 = kT[b] * qT[b]^T
    gemm_s<1, 0, 0><<<dim3(1, 1, 128), 512, SMEM, stream>>>(kqT, kqT + 1280, sc, nullptr, nullptr, nullptr,
        256, 256, 1280, 2560, 2560, 655360, 655360, 65536, 256);
    softmax_batch<<<256, 256, 0, stream>>>(sc, attn);
    // att2 (B,256,1280) = attn[b] * v[b]^T
    gemm_s<0, 0, 0><<<dim3(5, 1, 128), 512, SMEM, stream>>>(attn, vv, att2, nullptr, nullptr, nullptr,
        256, 1280, 256, 256, 256, 65536, 327680, 327680, 1280);
    // out f32 (B,C,HW) = alpha*(Wr*att2^T + br[row]) + x;  B large -> ORDER=0
    gemm_s<3, 2, 0><<<dim3(640, 1, 1), 512, SMEM, stream>>>(Wrb, att2, d_out, br, x, al,
        1280, 32768, 1280, 1280, 1280, 0, 0, 0, 0);
}